// Round 1
// baseline (4398.467 us; speedup 1.0000x reference)
//
#include <hip/hip_runtime.h>

// ---------------------------------------------------------------------------
// Transducer forward (RNN-T): 2-layer LSTM encoder + 1-layer LSTM decoder +
// fused joint (tanh MLP -> logits). fp16 MFMA for all matmuls, fp32 states.
// Tolerance is ~2% of max|ref| -> fp16 matmul inputs are safely within budget.
// ---------------------------------------------------------------------------

typedef _Float16 f16;
typedef _Float16 f16x8 __attribute__((ext_vector_type(8)));
typedef float f32x4 __attribute__((ext_vector_type(4)));
using u32 = unsigned int;

#define BB   8
#define TT   256
#define UU1  65      // U+1
#define HH   512
#define G4   2048    // 4*H
#define PP   512
#define JJ   512
#define VV   1024

static __device__ __forceinline__ u32 packf16(float a, float b) {
  f16 ha = (f16)a, hb = (f16)b;
  unsigned short ua = __builtin_bit_cast(unsigned short, ha);
  unsigned short ub = __builtin_bit_cast(unsigned short, hb);
  return (u32)ua | ((u32)ub << 16);
}
static __device__ __forceinline__ float sigm(float x) {
  x = fminf(30.f, fmaxf(-30.f, x));
  return __builtin_amdgcn_rcpf(1.f + __expf(-x));
}
static __device__ __forceinline__ float ftanh(float x) {
  x = fminf(15.f, fmaxf(-15.f, x));
  float t = __expf(2.f * x);
  return (t - 1.f) * __builtin_amdgcn_rcpf(t + 1.f);
}

// ---------------------------- utility kernels ------------------------------
__global__ void k_zero(u32* __restrict__ p, int n) {
  int i = blockIdx.x * 256 + threadIdx.x;
  if (i < n) p[i] = 0u;
}

__global__ void k_cast(const float* __restrict__ s, f16* __restrict__ d, int n4) {
  int i = blockIdx.x * 256 + threadIdx.x;
  if (i < n4) {
    const float4 v = *(const float4*)(s + (size_t)i * 4);
    u32 lo = packf16(v.x, v.y), hi = packf16(v.z, v.w);
    uint2 p; p.x = lo; p.y = hi;
    *(uint2*)(d + (size_t)i * 4) = p;
  }
}

// e[row][0:512] = embed[ys_p[row]] ; row = b*65+u ; ys_p[b][0]=BOS=0
__global__ void k_embed(const int* __restrict__ ys, const float* __restrict__ emb,
                        float* __restrict__ e) {
  int row = blockIdx.x;                 // 0..519
  int b = row / UU1, u = row % UU1;
  int idx = (u == 0) ? 0 : ys[b * (UU1 - 1) + (u - 1)];
  const float4* s = (const float4*)(emb + (size_t)idx * HH);
  float4* d = (float4*)(e + (size_t)row * HH);
  d[threadIdx.x] = s[threadIdx.x];      // 128 threads x 16B = 2KB
}

// ------------------------------ generic GEMM -------------------------------
// C[M,N] = A[M,lda](f32) * B[N,ldb](f16)^T (+ bias[n]); MFMA f16 16x16x32.
// Tile 128x128, 256 threads (4 waves, 2x2), BK=64 single-buffered.
__global__ __launch_bounds__(256) void k_gemm(
    const float* __restrict__ A, const f16* __restrict__ B,
    const float* __restrict__ bias, float* __restrict__ C,
    int M, int N, int K, int lda, int ldb) {
  __shared__ f16 As[128][72];
  __shared__ f16 Bs[128][72];
  int tid = threadIdx.x;
  int mb = blockIdx.y * 128, nb = blockIdx.x * 128;
  int wave = tid >> 6, lane = tid & 63;
  int wm = wave >> 1, wn = wave & 1;
  int rowa = lane & 15, kg = lane >> 4;
  f32x4 acc[4][4] = {};
  for (int k0 = 0; k0 < K; k0 += 64) {
    // stage A (f32 -> f16)
    for (int idx = tid; idx < 2048; idx += 256) {
      int r = idx >> 4, cq = idx & 15;
      int gm = mb + r, gk = k0 + cq * 4;
      float4 v = make_float4(0.f, 0.f, 0.f, 0.f);
      if (gm < M && gk + 3 < K) v = *(const float4*)(A + (size_t)gm * lda + gk);
      uint2 p; p.x = packf16(v.x, v.y); p.y = packf16(v.z, v.w);
      *(uint2*)&As[r][cq * 4] = p;
    }
    // stage B (f16 copy)
    for (int idx = tid; idx < 1024; idx += 256) {
      int r = idx >> 3, c8 = idx & 7;
      int gn = nb + r, gk = k0 + c8 * 8;
      uint4 v = make_uint4(0u, 0u, 0u, 0u);
      if (gn < N && gk + 7 < K) v = *(const uint4*)(B + (size_t)gn * ldb + gk);
      *(uint4*)&Bs[r][c8 * 8] = v;
    }
    __syncthreads();
#pragma unroll
    for (int kf = 0; kf < 2; ++kf) {
      f16x8 af[4], bf[4];
#pragma unroll
      for (int mt = 0; mt < 4; ++mt)
        af[mt] = *(const f16x8*)&As[wm * 64 + mt * 16 + rowa][kf * 32 + kg * 8];
#pragma unroll
      for (int nt = 0; nt < 4; ++nt)
        bf[nt] = *(const f16x8*)&Bs[wn * 64 + nt * 16 + rowa][kf * 32 + kg * 8];
#pragma unroll
      for (int mt = 0; mt < 4; ++mt)
#pragma unroll
        for (int nt = 0; nt < 4; ++nt)
          acc[mt][nt] = __builtin_amdgcn_mfma_f32_16x16x32_f16(af[mt], bf[nt], acc[mt][nt], 0, 0, 0);
    }
    __syncthreads();
  }
#pragma unroll
  for (int nt = 0; nt < 4; ++nt) {
    int gn = nb + wn * 64 + nt * 16 + rowa;
    float bv = bias ? bias[gn] : 0.f;
#pragma unroll
    for (int mt = 0; mt < 4; ++mt)
#pragma unroll
      for (int r = 0; r < 4; ++r) {
        int gm = mb + wm * 64 + mt * 16 + kg * 4 + r;
        if (gm < M) C[(size_t)gm * N + gn] = acc[mt][nt][r] + bv;
      }
  }
}

// ------------------------------ persistent LSTM ----------------------------
// One layer, S steps. 16 WGs x 256 threads; WG wg owns hidden units
// [wg*32, wg*32+32) -> 128 gate rows, Whh slice resident in LDS (f16).
// h exchanged via agent-scope atomics in hbuf[2][8][512] (f16 pairs as u32);
// per-WG release flags provide the inter-step barrier.
__global__ __launch_bounds__(256) void k_lstm(
    const float* __restrict__ xp,   // [B*S][2048] precomputed input proj (+bias)
    const f16* __restrict__ W,      // [2048][512] f16 Whh
    u32* __restrict__ hbuf,         // [2][8][512] f16 (as u32 pairs), zero-init
    float* __restrict__ hs,         // [B*S][512] f32 out
    int* __restrict__ flags,        // [16], zero-init
    int S) {
  extern __shared__ char smem[];
  f16 (*Wlds)[520] = (f16(*)[520])smem;                       // 133,120 B
  f16 (*Hlds)[520] = (f16(*)[520])(smem + 133120);            //  16,640 B
  float (*gat)[132] = (float(*)[132])(smem + 133120 + 16640); //   4,224 B
  int wg = blockIdx.x, tid = threadIdx.x;
  int u0 = wg * 32;

  // stage Whh slice: LDS row r = g*32+j  <->  global row g*512 + u0 + j
  for (int idx = tid; idx < 128 * 64; idx += 256) {
    int r = idx >> 6, ck = idx & 63;
    int g = r >> 5, j = r & 31;
    uint4 v = *(const uint4*)(W + ((size_t)(g * 512 + u0 + j)) * 512 + ck * 8);
    *(uint4*)&Wlds[r][ck * 8] = v;
  }
  // zero Hlds (rows 8..15 = M padding stay zero forever)
  for (int idx = tid; idx < 16 * 260; idx += 256) ((u32*)Hlds)[idx] = 0u;
  __syncthreads();

  int wave = tid >> 6, lane = tid & 63;
  int rowa = lane & 15, kg = lane >> 4;
  int b = tid >> 5, j = tid & 31;
  float c = 0.f;

  for (int t = 0; t < S; ++t) {
    if (t > 0) {
      if (tid < 16) {
        while (__hip_atomic_load(&flags[tid], __ATOMIC_ACQUIRE, __HIP_MEMORY_SCOPE_AGENT) < t)
          __builtin_amdgcn_s_sleep(1);
      }
      __syncthreads();
    }
    // stage h(t-1) rows 0..7 into LDS (agent-scope loads -> coherent)
    {
      u32* hb = hbuf + (size_t)(t & 1) * 2048;
      for (int idx = tid; idx < 2048; idx += 256) {
        int r = idx >> 8, cu = idx & 255;
        u32 w = __hip_atomic_load(hb + r * 256 + cu, __ATOMIC_RELAXED, __HIP_MEMORY_SCOPE_AGENT);
        ((u32*)Hlds)[r * 260 + cu] = w;
      }
    }
    __syncthreads();

    // gates[16][128] = h(t-1) @ Wslice^T  (wave w -> cols [w*32, w*32+32))
    f32x4 acc0 = {0.f, 0.f, 0.f, 0.f}, acc1 = {0.f, 0.f, 0.f, 0.f};
#pragma unroll
    for (int kf = 0; kf < 16; ++kf) {
      f16x8 af = *(const f16x8*)&Hlds[rowa][kf * 32 + kg * 8];
      f16x8 b0 = *(const f16x8*)&Wlds[wave * 32 + rowa][kf * 32 + kg * 8];
      f16x8 b1 = *(const f16x8*)&Wlds[wave * 32 + 16 + rowa][kf * 32 + kg * 8];
      acc0 = __builtin_amdgcn_mfma_f32_16x16x32_f16(af, b0, acc0, 0, 0, 0);
      acc1 = __builtin_amdgcn_mfma_f32_16x16x32_f16(af, b1, acc1, 0, 0, 0);
    }
    if (kg < 2) {   // C rows 0..7 valid (batch), 8..15 are padding
#pragma unroll
      for (int r = 0; r < 4; ++r) {
        gat[kg * 4 + r][wave * 32 + rowa] = acc0[r];
        gat[kg * 4 + r][wave * 32 + 16 + rowa] = acc1[r];
      }
    }
    __syncthreads();

    // scalar phase: thread -> (b, unit j)
    size_t xpo = ((size_t)b * S + t) * (size_t)G4 + u0 + j;
    float gi = gat[b][j]       + xp[xpo];
    float gf = gat[b][32 + j]  + xp[xpo + 512];
    float gg = gat[b][64 + j]  + xp[xpo + 1024];
    float go = gat[b][96 + j]  + xp[xpo + 1536];
    c = sigm(gf) * c + sigm(gi) * ftanh(gg);
    float h = sigm(go) * ftanh(c);
    hs[((size_t)b * S + t) * HH + u0 + j] = h;

    float hn = __shfl_down(h, 1);
    u32* hbn = hbuf + (size_t)((t + 1) & 1) * 2048;
    if ((j & 1) == 0)
      __hip_atomic_store(hbn + ((b * 512 + u0 + j) >> 1), packf16(h, hn),
                         __ATOMIC_RELAXED, __HIP_MEMORY_SCOPE_AGENT);
    __threadfence();
    __syncthreads();
    if (tid == 0)
      __hip_atomic_store(&flags[wg], t + 1, __ATOMIC_RELEASE, __HIP_MEMORY_SCOPE_AGENT);
  }
}

// ------------------------------ fused joint --------------------------------
// out[m][v] = sum_j tanh(pre_enc[bt(m)][j] + pre_dec[bu(m)][j]) * jW2[v][j] + jb2[v]
// WG: 128 consecutive m rows; z tile in LDS (f16); jW2 f16 streamed from L2.
__global__ __launch_bounds__(512) void k_joint(
    const float* __restrict__ pre_enc,   // [B*T][512]   (no bias)
    const float* __restrict__ pre_dec,   // [B*65][512]  (jb1 folded in)
    const f16* __restrict__ jW2,         // [1024][512] f16
    const float* __restrict__ jb2,
    float* __restrict__ out) {
  extern __shared__ char smem[];
  f16 (*Z)[520] = (f16(*)[520])smem;     // 133,120 B
  int tid = threadIdx.x;
  int m0 = blockIdx.x * 128;
  {
    int r = tid >> 2, q = tid & 3;
    int m = m0 + r;
    int bb = m / (TT * UU1);
    int rem = m % (TT * UU1);
    int t = rem / UU1, u = rem % UU1;
    const float* pe = pre_enc + ((size_t)bb * TT + t) * JJ + q * 128;
    const float* pd = pre_dec + ((size_t)bb * UU1 + u) * JJ + q * 128;
    for (int i = 0; i < 128; i += 8) {
      float4 e0 = *(const float4*)(pe + i);
      float4 e1 = *(const float4*)(pe + i + 4);
      float4 d0 = *(const float4*)(pd + i);
      float4 d1 = *(const float4*)(pd + i + 4);
      float z0 = ftanh(e0.x + d0.x), z1 = ftanh(e0.y + d0.y);
      float z2 = ftanh(e0.z + d0.z), z3 = ftanh(e0.w + d0.w);
      float z4 = ftanh(e1.x + d1.x), z5 = ftanh(e1.y + d1.y);
      float z6 = ftanh(e1.z + d1.z), z7 = ftanh(e1.w + d1.w);
      uint4 p; p.x = packf16(z0, z1); p.y = packf16(z2, z3);
      p.z = packf16(z4, z5); p.w = packf16(z6, z7);
      *(uint4*)&Z[r][q * 128 + i] = p;
    }
  }
  __syncthreads();
  int wave = tid >> 6, lane = tid & 63;
  int wm = wave >> 2, wn = wave & 3;
  int rowa = lane & 15, kg = lane >> 4;
  for (int ch = 0; ch < 4; ++ch) {       // 4 N-chunks of 256
    f32x4 acc[4][4] = {};
    int nb = ch * 256 + wn * 64;
    for (int kf = 0; kf < 16; ++kf) {
      f16x8 af[4], bf[4];
#pragma unroll
      for (int mt = 0; mt < 4; ++mt)
        af[mt] = *(const f16x8*)&Z[wm * 64 + mt * 16 + rowa][kf * 32 + kg * 8];
#pragma unroll
      for (int nt = 0; nt < 4; ++nt)
        bf[nt] = *(const f16x8*)(jW2 + (size_t)(nb + nt * 16 + rowa) * JJ + kf * 32 + kg * 8);
#pragma unroll
      for (int mt = 0; mt < 4; ++mt)
#pragma unroll
        for (int nt = 0; nt < 4; ++nt)
          acc[mt][nt] = __builtin_amdgcn_mfma_f32_16x16x32_f16(af[mt], bf[nt], acc[mt][nt], 0, 0, 0);
    }
#pragma unroll
    for (int nt = 0; nt < 4; ++nt) {
      int v = nb + nt * 16 + rowa;
      float bv = jb2[v];
#pragma unroll
      for (int mt = 0; mt < 4; ++mt)
#pragma unroll
        for (int r = 0; r < 4; ++r) {
          int m = m0 + wm * 64 + mt * 16 + kg * 4 + r;
          out[(size_t)m * VV + v] = acc[mt][nt][r] + bv;
        }
    }
  }
}

// ------------------------------- host side ---------------------------------
extern "C" void kernel_launch(void* const* d_in, const int* in_sizes, int n_in,
                              void* d_out, int out_size, void* d_ws, size_t ws_size,
                              hipStream_t stream) {
  const float* xs    = (const float*)d_in[0];
  const int*   ys    = (const int*)d_in[1];
  const float* Wih0  = (const float*)d_in[2];
  const float* Whh0  = (const float*)d_in[3];
  const float* b0    = (const float*)d_in[4];
  const float* Wih1  = (const float*)d_in[5];
  const float* Whh1  = (const float*)d_in[6];
  const float* b1    = (const float*)d_in[7];
  const float* encPW = (const float*)d_in[8];
  const float* encPb = (const float*)d_in[9];
  const float* embed = (const float*)d_in[10];
  const float* dWih  = (const float*)d_in[11];
  const float* dWhh  = (const float*)d_in[12];
  const float* db    = (const float*)d_in[13];
  const float* dPW   = (const float*)d_in[14];
  const float* dPb   = (const float*)d_in[15];
  const float* jW1   = (const float*)d_in[16];
  const float* jb1   = (const float*)d_in[17];
  const float* jW2   = (const float*)d_in[18];
  const float* jb2   = (const float*)d_in[19];
  float* out = (float*)d_out;

  char* base = (char*)d_ws;
  size_t off = 0;
  auto alc = [&](size_t bytes) -> char* {
    char* p = base + off;
    off = (off + bytes + 255) & ~(size_t)255;
    return p;
  };
  f16* Wih0h = (f16*)alc((size_t)2048 * 80 * 2);
  f16* Whh0h = (f16*)alc((size_t)2048 * 512 * 2);
  f16* Wih1h = (f16*)alc((size_t)2048 * 512 * 2);
  f16* Whh1h = (f16*)alc((size_t)2048 * 512 * 2);
  f16* dWihh = (f16*)alc((size_t)2048 * 512 * 2);
  f16* dWhhh = (f16*)alc((size_t)2048 * 512 * 2);
  f16* ePWh  = (f16*)alc((size_t)512 * 512 * 2);
  f16* dPWh  = (f16*)alc((size_t)512 * 512 * 2);
  f16* jW1h  = (f16*)alc((size_t)512 * 1024 * 2);
  f16* jW2h  = (f16*)alc((size_t)1024 * 512 * 2);
  float* e    = (float*)alc((size_t)520 * 512 * 4);
  float* xp0  = (float*)alc((size_t)2048 * 2048 * 4);
  float* xpd  = (float*)alc((size_t)520 * 2048 * 4);
  float* xp1  = (float*)alc((size_t)2048 * 2048 * 4);
  float* h0s  = (float*)alc((size_t)2048 * 512 * 4);
  float* h1s  = (float*)alc((size_t)2048 * 512 * 4);
  float* hds  = (float*)alc((size_t)520 * 512 * 4);
  float* henc = (float*)alc((size_t)2048 * 512 * 4);
  float* hdec = (float*)alc((size_t)520 * 512 * 4);
  float* penc = (float*)alc((size_t)2048 * 512 * 4);
  float* pdec = (float*)alc((size_t)520 * 512 * 4);
  char* sync_beg = alc(0);
  u32* hbA = (u32*)alc((size_t)2 * 8 * 512 * 2);
  u32* hbB = (u32*)alc((size_t)2 * 8 * 512 * 2);
  u32* hbD = (u32*)alc((size_t)2 * 8 * 512 * 2);
  int* flA = (int*)alc(64);
  int* flB = (int*)alc(64);
  int* flD = (int*)alc(64);
  size_t zbytes = (size_t)((base + off) - sync_beg);
  if (off > ws_size) return;  // workspace too small (should not happen)

  // 1) zero sync region (hbufs + flags) -- must precede all LSTM launches
  {
    int n = (int)(zbytes / 4);
    k_zero<<<dim3((n + 255) / 256), dim3(256), 0, stream>>>((u32*)sync_beg, n);
  }
  // 2) cast weights to f16
  auto cast = [&](const float* s, f16* d, size_t n) {
    int n4 = (int)(n / 4);
    k_cast<<<dim3((n4 + 255) / 256), dim3(256), 0, stream>>>(s, d, n4);
  };
  cast(Wih0, Wih0h, (size_t)2048 * 80);
  cast(Whh0, Whh0h, (size_t)2048 * 512);
  cast(Wih1, Wih1h, (size_t)2048 * 512);
  cast(Whh1, Whh1h, (size_t)2048 * 512);
  cast(dWih, dWihh, (size_t)2048 * 512);
  cast(dWhh, dWhhh, (size_t)2048 * 512);
  cast(encPW, ePWh, (size_t)512 * 512);
  cast(dPW, dPWh, (size_t)512 * 512);
  cast(jW1, jW1h, (size_t)512 * 1024);
  cast(jW2, jW2h, (size_t)1024 * 512);

  // 3) embedding (decoder input)
  k_embed<<<dim3(520), dim3(128), 0, stream>>>(ys, embed, e);

  auto gemm = [&](const float* A, const f16* B, const float* bias, float* C,
                  int M, int N, int K, int lda, int ldb) {
    k_gemm<<<dim3(N / 128, (M + 127) / 128), dim3(256), 0, stream>>>(
        A, B, bias, C, M, N, K, lda, ldb);
  };

  const size_t LSTM_LDS = 133120 + 16640 + 4224;   // 153,984 B

  // 4) encoder
  gemm(xs, Wih0h, b0, xp0, 2048, 2048, 80, 80, 80);
  k_lstm<<<dim3(16), dim3(256), LSTM_LDS, stream>>>(xp0, Whh0h, hbA, h0s, flA, 256);
  gemm(h0s, Wih1h, b1, xp1, 2048, 2048, 512, 512, 512);
  k_lstm<<<dim3(16), dim3(256), LSTM_LDS, stream>>>(xp1, Whh1h, hbB, h1s, flB, 256);
  gemm(h1s, ePWh, encPb, henc, 2048, 512, 512, 512, 512);
  gemm(henc, jW1h, nullptr, penc, 2048, 512, 512, 512, 1024);

  // 5) decoder
  gemm(e, dWihh, db, xpd, 520, 2048, 512, 512, 512);
  k_lstm<<<dim3(16), dim3(256), LSTM_LDS, stream>>>(xpd, dWhhh, hbD, hds, flD, 65);
  gemm(hds, dPWh, dPb, hdec, 520, 512, 512, 512, 512);
  gemm(hdec, jW1h + 512, jb1, pdec, 520, 512, 512, 512, 1024);  // jb1 folded here

  // 6) fused joint: z = tanh(penc+pdec) ; out = z @ jW2^T + jb2
  k_joint<<<dim3(1040), dim3(512), 133120, stream>>>(penc, pdec, jW2h, jb2, out);
}

// Round 2
// 2875.366 us; speedup vs baseline: 1.5297x; 1.5297x over previous
//
#include <hip/hip_runtime.h>

// ---------------------------------------------------------------------------
// Transducer forward (RNN-T): 2-layer LSTM encoder + 1-layer LSTM decoder +
// fused joint (tanh MLP -> logits). fp16 MFMA for all matmuls, fp32 states.
// R1: LSTM sync via RELAXED agent atomics (sc1/LLC) + vmcnt drain only --
//     no buffer_inv/wbl2 per step; Whh in VGPRs; decoder fused with enc L0.
// ---------------------------------------------------------------------------

typedef _Float16 f16;
typedef _Float16 f16x8 __attribute__((ext_vector_type(8)));
typedef float f32x4 __attribute__((ext_vector_type(4)));
using u32 = unsigned int;

#define BB   8
#define TT   256
#define UU1  65      // U+1
#define HH   512
#define G4   2048    // 4*H
#define PP   512
#define JJ   512
#define VV   1024

#define LOADX(p)     __hip_atomic_load((p), __ATOMIC_RELAXED, __HIP_MEMORY_SCOPE_AGENT)
#define STOREX(p, v) __hip_atomic_store((p), (v), __ATOMIC_RELAXED, __HIP_MEMORY_SCOPE_AGENT)

static __device__ __forceinline__ u32 packf16(float a, float b) {
  f16 ha = (f16)a, hb = (f16)b;
  unsigned short ua = __builtin_bit_cast(unsigned short, ha);
  unsigned short ub = __builtin_bit_cast(unsigned short, hb);
  return (u32)ua | ((u32)ub << 16);
}
static __device__ __forceinline__ float sigm(float x) {
  x = fminf(30.f, fmaxf(-30.f, x));
  return __builtin_amdgcn_rcpf(1.f + __expf(-x));
}
static __device__ __forceinline__ float ftanh(float x) {
  x = fminf(15.f, fmaxf(-15.f, x));
  float t = __expf(2.f * x);
  return (t - 1.f) * __builtin_amdgcn_rcpf(t + 1.f);
}

// ---------------------------- utility kernels ------------------------------
__global__ void k_zero(u32* __restrict__ p, int n) {
  int i = blockIdx.x * 256 + threadIdx.x;
  if (i < n) p[i] = 0u;
}

__global__ void k_cast(const float* __restrict__ s, f16* __restrict__ d, int n4) {
  int i = blockIdx.x * 256 + threadIdx.x;
  if (i < n4) {
    const float4 v = *(const float4*)(s + (size_t)i * 4);
    u32 lo = packf16(v.x, v.y), hi = packf16(v.z, v.w);
    uint2 p; p.x = lo; p.y = hi;
    *(uint2*)(d + (size_t)i * 4) = p;
  }
}

// e[row][0:512] = embed[ys_p[row]] ; row = b*65+u ; ys_p[b][0]=BOS=0
__global__ void k_embed(const int* __restrict__ ys, const float* __restrict__ emb,
                        float* __restrict__ e) {
  int row = blockIdx.x;                 // 0..519
  int b = row / UU1, u = row % UU1;
  int idx = (u == 0) ? 0 : ys[b * (UU1 - 1) + (u - 1)];
  const float4* s = (const float4*)(emb + (size_t)idx * HH);
  float4* d = (float4*)(e + (size_t)row * HH);
  d[threadIdx.x] = s[threadIdx.x];      // 128 threads x 16B = 2KB
}

// ------------------------------ generic GEMM -------------------------------
// C[M,N] = A[M,lda](f32) * B[N,ldb](f16)^T (+ bias[n]); MFMA f16 16x16x32.
__global__ __launch_bounds__(256) void k_gemm(
    const float* __restrict__ A, const f16* __restrict__ B,
    const float* __restrict__ bias, float* __restrict__ C,
    int M, int N, int K, int lda, int ldb) {
  __shared__ f16 As[128][72];
  __shared__ f16 Bs[128][72];
  int tid = threadIdx.x;
  int mb = blockIdx.y * 128, nb = blockIdx.x * 128;
  int wave = tid >> 6, lane = tid & 63;
  int wm = wave >> 1, wn = wave & 1;
  int rowa = lane & 15, kg = lane >> 4;
  f32x4 acc[4][4] = {};
  for (int k0 = 0; k0 < K; k0 += 64) {
    for (int idx = tid; idx < 2048; idx += 256) {
      int r = idx >> 4, cq = idx & 15;
      int gm = mb + r, gk = k0 + cq * 4;
      float4 v = make_float4(0.f, 0.f, 0.f, 0.f);
      if (gm < M && gk + 3 < K) v = *(const float4*)(A + (size_t)gm * lda + gk);
      uint2 p; p.x = packf16(v.x, v.y); p.y = packf16(v.z, v.w);
      *(uint2*)&As[r][cq * 4] = p;
    }
    for (int idx = tid; idx < 1024; idx += 256) {
      int r = idx >> 3, c8 = idx & 7;
      int gn = nb + r, gk = k0 + c8 * 8;
      uint4 v = make_uint4(0u, 0u, 0u, 0u);
      if (gn < N && gk + 7 < K) v = *(const uint4*)(B + (size_t)gn * ldb + gk);
      *(uint4*)&Bs[r][c8 * 8] = v;
    }
    __syncthreads();
#pragma unroll
    for (int kf = 0; kf < 2; ++kf) {
      f16x8 af[4], bf[4];
#pragma unroll
      for (int mt = 0; mt < 4; ++mt)
        af[mt] = *(const f16x8*)&As[wm * 64 + mt * 16 + rowa][kf * 32 + kg * 8];
#pragma unroll
      for (int nt = 0; nt < 4; ++nt)
        bf[nt] = *(const f16x8*)&Bs[wn * 64 + nt * 16 + rowa][kf * 32 + kg * 8];
#pragma unroll
      for (int mt = 0; mt < 4; ++mt)
#pragma unroll
        for (int nt = 0; nt < 4; ++nt)
          acc[mt][nt] = __builtin_amdgcn_mfma_f32_16x16x32_f16(af[mt], bf[nt], acc[mt][nt], 0, 0, 0);
    }
    __syncthreads();
  }
#pragma unroll
  for (int nt = 0; nt < 4; ++nt) {
    int gn = nb + wn * 64 + nt * 16 + rowa;
    float bv = bias ? bias[gn] : 0.f;
#pragma unroll
    for (int mt = 0; mt < 4; ++mt)
#pragma unroll
      for (int r = 0; r < 4; ++r) {
        int gm = mb + wm * 64 + mt * 16 + kg * 4 + r;
        if (gm < M) C[(size_t)gm * N + gn] = acc[mt][nt][r] + bv;
      }
  }
}

// ------------------------------ persistent LSTM ----------------------------
// One layer, S steps. 16 WGs x 256 threads; WG wg owns hidden units
// [wg*32, wg*32+32) -> 128 gate rows; Whh fragments live in VGPRs.
// h exchanged via RELAXED agent-scope atomics (sc1 -> LLC coherence point);
// ordering: __syncthreads() drains vmcnt before the flag release store.
static __device__ __forceinline__ void lstm_body(
    int wg, const float* __restrict__ xp, const f16* __restrict__ W,
    u32* __restrict__ hbuf, float* __restrict__ hs, int* __restrict__ flags,
    int S) {
  __shared__ f16 Hlds[16][520];
  __shared__ float gat[8][132];
  int tid = threadIdx.x;
  int u0 = wg * 32;
  int wave = tid >> 6, lane = tid & 63;
  int rowa = lane & 15, kg = lane >> 4;
  int b = tid >> 5, j = tid & 31;

  // Whh fragments -> registers (invariant over t).
  // B-frag rows for this thread: gate row (wave*512 + u0 + rowa) and +16.
  const f16* wb0 = W + ((size_t)(wave * 512 + u0 + rowa)) * 512 + kg * 8;
  const f16* wb1 = wb0 + (size_t)16 * 512;
  f16x8 w0[16], w1[16];
#pragma unroll
  for (int kf = 0; kf < 16; ++kf) {
    w0[kf] = *(const f16x8*)(wb0 + kf * 32);
    w1[kf] = *(const f16x8*)(wb1 + kf * 32);
  }
  // zero Hlds (rows 8..15 = M padding stay zero forever)
  for (int idx = tid; idx < 16 * 260; idx += 256) ((u32*)Hlds)[idx] = 0u;

  float c = 0.f;
  for (int t = 0; t < S; ++t) {
    if (t > 0) {
      if (tid < 16) {
        int guard = 0;
        while (LOADX(flags + tid) < t && ++guard < (1 << 20)) { }
      }
    }
    __syncthreads();  // B1: flag observed (and t=0: Hlds zeros visible)

    // stage h(t-1) rows 0..7 into LDS (relaxed sc1 loads from LLC)
    {
      u32* hb = hbuf + (size_t)(t & 1) * 2048;
      for (int k = 0; k < 8; ++k) {
        int idx = tid + k * 256;
        int r = idx >> 8, cu = idx & 255;
        ((u32*)Hlds)[r * 260 + cu] = LOADX(hb + r * 256 + cu);
      }
    }
    // xp gather issued here; consumed after B3 (hidden under staging+MFMA)
    size_t xpo = ((size_t)b * S + t) * (size_t)G4 + u0 + j;
    float xi = xp[xpo];
    float xf = xp[xpo + 512];
    float xg = xp[xpo + 1024];
    float xo = xp[xpo + 1536];
    __syncthreads();  // B2: Hlds ready

    // gates[16][128] = h(t-1) @ Wslice^T  (wave w -> gate quarter w)
    f32x4 acc0 = {0.f, 0.f, 0.f, 0.f}, acc1 = {0.f, 0.f, 0.f, 0.f};
#pragma unroll
    for (int kf = 0; kf < 16; ++kf) {
      f16x8 af = *(const f16x8*)&Hlds[rowa][kf * 32 + kg * 8];
      acc0 = __builtin_amdgcn_mfma_f32_16x16x32_f16(af, w0[kf], acc0, 0, 0, 0);
      acc1 = __builtin_amdgcn_mfma_f32_16x16x32_f16(af, w1[kf], acc1, 0, 0, 0);
    }
    if (kg < 2) {   // C rows 0..7 valid (batch), 8..15 are padding
#pragma unroll
      for (int r = 0; r < 4; ++r) {
        gat[kg * 4 + r][wave * 32 + rowa] = acc0[r];
        gat[kg * 4 + r][wave * 32 + 16 + rowa] = acc1[r];
      }
    }
    __syncthreads();  // B3: gat ready

    // scalar phase: thread -> (b, unit j)
    float gi = gat[b][j] + xi;
    float gf = gat[b][32 + j] + xf;
    float gg = gat[b][64 + j] + xg;
    float go = gat[b][96 + j] + xo;
    c = sigm(gf) * c + sigm(gi) * ftanh(gg);
    float h = sigm(go) * ftanh(c);

    float hn = __shfl_down(h, 1);
    u32* hbn = hbuf + (size_t)((t + 1) & 1) * 2048;
    if ((j & 1) == 0)
      STOREX(hbn + ((b * 512 + u0 + j) >> 1), packf16(h, hn));
    __syncthreads();  // B4: drains vmcnt(0) -> h stores complete at LLC
    if (tid == 0) STOREX(&flags[wg], t + 1);
    hs[((size_t)b * S + t) * HH + u0 + j] = h;  // after flag: overlaps next spin
  }
}

__global__ __launch_bounds__(256, 1) void k_lstm(
    const float* xp, const f16* W, u32* hb, float* hs, int* fl, int S) {
  lstm_body(blockIdx.x, xp, W, hb, hs, fl, S);
}

// enc layer 0 (WGs 0..15) + decoder (WGs 16..31) in one dispatch
__global__ __launch_bounds__(256, 1) void k_lstm2(
    const float* xpA, const f16* WA, u32* hbA, float* hsA, int* flA, int SA,
    const float* xpB, const f16* WB, u32* hbB, float* hsB, int* flB, int SB) {
  if (blockIdx.x < 16) lstm_body(blockIdx.x, xpA, WA, hbA, hsA, flA, SA);
  else                 lstm_body(blockIdx.x - 16, xpB, WB, hbB, hsB, flB, SB);
}

// ------------------------------ fused joint --------------------------------
__global__ __launch_bounds__(512) void k_joint(
    const float* __restrict__ pre_enc,   // [B*T][512]   (no bias)
    const float* __restrict__ pre_dec,   // [B*65][512]  (jb1 folded in)
    const f16* __restrict__ jW2,         // [1024][512] f16
    const float* __restrict__ jb2,
    float* __restrict__ out) {
  extern __shared__ char smem[];
  f16 (*Z)[520] = (f16(*)[520])smem;     // 133,120 B
  int tid = threadIdx.x;
  int m0 = blockIdx.x * 128;
  {
    int r = tid >> 2, q = tid & 3;
    int m = m0 + r;
    int bb = m / (TT * UU1);
    int rem = m % (TT * UU1);
    int t = rem / UU1, u = rem % UU1;
    const float* pe = pre_enc + ((size_t)bb * TT + t) * JJ + q * 128;
    const float* pd = pre_dec + ((size_t)bb * UU1 + u) * JJ + q * 128;
    for (int i = 0; i < 128; i += 8) {
      float4 e0 = *(const float4*)(pe + i);
      float4 e1 = *(const float4*)(pe + i + 4);
      float4 d0 = *(const float4*)(pd + i);
      float4 d1 = *(const float4*)(pd + i + 4);
      float z0 = ftanh(e0.x + d0.x), z1 = ftanh(e0.y + d0.y);
      float z2 = ftanh(e0.z + d0.z), z3 = ftanh(e0.w + d0.w);
      float z4 = ftanh(e1.x + d1.x), z5 = ftanh(e1.y + d1.y);
      float z6 = ftanh(e1.z + d1.z), z7 = ftanh(e1.w + d1.w);
      uint4 p; p.x = packf16(z0, z1); p.y = packf16(z2, z3);
      p.z = packf16(z4, z5); p.w = packf16(z6, z7);
      *(uint4*)&Z[r][q * 128 + i] = p;
    }
  }
  __syncthreads();
  int wave = tid >> 6, lane = tid & 63;
  int wm = wave >> 2, wn = wave & 3;
  int rowa = lane & 15, kg = lane >> 4;
  for (int ch = 0; ch < 4; ++ch) {       // 4 N-chunks of 256
    f32x4 acc[4][4] = {};
    int nb = ch * 256 + wn * 64;
    for (int kf = 0; kf < 16; ++kf) {
      f16x8 af[4], bf[4];
#pragma unroll
      for (int mt = 0; mt < 4; ++mt)
        af[mt] = *(const f16x8*)&Z[wm * 64 + mt * 16 + rowa][kf * 32 + kg * 8];
#pragma unroll
      for (int nt = 0; nt < 4; ++nt)
        bf[nt] = *(const f16x8*)(jW2 + (size_t)(nb + nt * 16 + rowa) * JJ + kf * 32 + kg * 8);
#pragma unroll
      for (int mt = 0; mt < 4; ++mt)
#pragma unroll
        for (int nt = 0; nt < 4; ++nt)
          acc[mt][nt] = __builtin_amdgcn_mfma_f32_16x16x32_f16(af[mt], bf[nt], acc[mt][nt], 0, 0, 0);
    }
#pragma unroll
    for (int nt = 0; nt < 4; ++nt) {
      int v = nb + nt * 16 + rowa;
      float bv = jb2[v];
#pragma unroll
      for (int mt = 0; mt < 4; ++mt)
#pragma unroll
        for (int r = 0; r < 4; ++r) {
          int m = m0 + wm * 64 + mt * 16 + kg * 4 + r;
          out[(size_t)m * VV + v] = acc[mt][nt][r] + bv;
        }
    }
  }
}

// ------------------------------- host side ---------------------------------
extern "C" void kernel_launch(void* const* d_in, const int* in_sizes, int n_in,
                              void* d_out, int out_size, void* d_ws, size_t ws_size,
                              hipStream_t stream) {
  const float* xs    = (const float*)d_in[0];
  const int*   ys    = (const int*)d_in[1];
  const float* Wih0  = (const float*)d_in[2];
  const float* Whh0  = (const float*)d_in[3];
  const float* b0    = (const float*)d_in[4];
  const float* Wih1  = (const float*)d_in[5];
  const float* Whh1  = (const float*)d_in[6];
  const float* b1    = (const float*)d_in[7];
  const float* encPW = (const float*)d_in[8];
  const float* encPb = (const float*)d_in[9];
  const float* embed = (const float*)d_in[10];
  const float* dWih  = (const float*)d_in[11];
  const float* dWhh  = (const float*)d_in[12];
  const float* db    = (const float*)d_in[13];
  const float* dPW   = (const float*)d_in[14];
  const float* dPb   = (const float*)d_in[15];
  const float* jW1   = (const float*)d_in[16];
  const float* jb1   = (const float*)d_in[17];
  const float* jW2   = (const float*)d_in[18];
  const float* jb2   = (const float*)d_in[19];
  float* out = (float*)d_out;

  char* base = (char*)d_ws;
  size_t off = 0;
  auto alc = [&](size_t bytes) -> char* {
    char* p = base + off;
    off = (off + bytes + 255) & ~(size_t)255;
    return p;
  };
  f16* Wih0h = (f16*)alc((size_t)2048 * 80 * 2);
  f16* Whh0h = (f16*)alc((size_t)2048 * 512 * 2);
  f16* Wih1h = (f16*)alc((size_t)2048 * 512 * 2);
  f16* Whh1h = (f16*)alc((size_t)2048 * 512 * 2);
  f16* dWihh = (f16*)alc((size_t)2048 * 512 * 2);
  f16* dWhhh = (f16*)alc((size_t)2048 * 512 * 2);
  f16* ePWh  = (f16*)alc((size_t)512 * 512 * 2);
  f16* dPWh  = (f16*)alc((size_t)512 * 512 * 2);
  f16* jW1h  = (f16*)alc((size_t)512 * 1024 * 2);
  f16* jW2h  = (f16*)alc((size_t)1024 * 512 * 2);
  float* e    = (float*)alc((size_t)520 * 512 * 4);
  float* xp0  = (float*)alc((size_t)2048 * 2048 * 4);
  float* xpd  = (float*)alc((size_t)520 * 2048 * 4);
  float* xp1  = (float*)alc((size_t)2048 * 2048 * 4);
  float* h0s  = (float*)alc((size_t)2048 * 512 * 4);
  float* h1s  = (float*)alc((size_t)2048 * 512 * 4);
  float* hds  = (float*)alc((size_t)520 * 512 * 4);
  float* henc = (float*)alc((size_t)2048 * 512 * 4);
  float* hdec = (float*)alc((size_t)520 * 512 * 4);
  float* penc = (float*)alc((size_t)2048 * 512 * 4);
  float* pdec = (float*)alc((size_t)520 * 512 * 4);
  char* sync_beg = alc(0);
  u32* hbA = (u32*)alc((size_t)2 * 8 * 512 * 2);
  u32* hbB = (u32*)alc((size_t)2 * 8 * 512 * 2);
  u32* hbD = (u32*)alc((size_t)2 * 8 * 512 * 2);
  int* flA = (int*)alc(64);
  int* flB = (int*)alc(64);
  int* flD = (int*)alc(64);
  size_t zbytes = (size_t)((base + off) - sync_beg);
  if (off > ws_size) return;

  // 1) zero sync region (hbufs + flags) -- must precede all LSTM launches
  {
    int n = (int)(zbytes / 4);
    k_zero<<<dim3((n + 255) / 256), dim3(256), 0, stream>>>((u32*)sync_beg, n);
  }
  // 2) cast weights to f16
  auto cast = [&](const float* s, f16* d, size_t n) {
    int n4 = (int)(n / 4);
    k_cast<<<dim3((n4 + 255) / 256), dim3(256), 0, stream>>>(s, d, n4);
  };
  cast(Wih0, Wih0h, (size_t)2048 * 80);
  cast(Whh0, Whh0h, (size_t)2048 * 512);
  cast(Wih1, Wih1h, (size_t)2048 * 512);
  cast(Whh1, Whh1h, (size_t)2048 * 512);
  cast(dWih, dWihh, (size_t)2048 * 512);
  cast(dWhh, dWhhh, (size_t)2048 * 512);
  cast(encPW, ePWh, (size_t)512 * 512);
  cast(dPW, dPWh, (size_t)512 * 512);
  cast(jW1, jW1h, (size_t)512 * 1024);
  cast(jW2, jW2h, (size_t)1024 * 512);

  // 3) embedding (decoder input)
  k_embed<<<dim3(520), dim3(128), 0, stream>>>(ys, embed, e);

  auto gemm = [&](const float* A, const f16* B, const float* bias, float* C,
                  int M, int N, int K, int lda, int ldb) {
    k_gemm<<<dim3(N / 128, (M + 127) / 128), dim3(256), 0, stream>>>(
        A, B, bias, C, M, N, K, lda, ldb);
  };

  // 4) input projections for enc L0 and decoder
  gemm(xs, Wih0h, b0, xp0, 2048, 2048, 80, 80, 80);
  gemm(e, dWihh, db, xpd, 520, 2048, 512, 512, 512);

  // 5) enc layer 0 LSTM + decoder LSTM fused in one dispatch (32 WGs)
  k_lstm2<<<dim3(32), dim3(256), 0, stream>>>(xp0, Whh0h, hbA, h0s, flA, 256,
                                              xpd, dWhhh, hbD, hds, flD, 65);

  // 6) enc layer 1
  gemm(h0s, Wih1h, b1, xp1, 2048, 2048, 512, 512, 512);
  k_lstm<<<dim3(16), dim3(256), 0, stream>>>(xp1, Whh1h, hbB, h1s, flB, 256);

  // 7) projections / joint pre-activations
  gemm(h1s, ePWh, encPb, henc, 2048, 512, 512, 512, 512);
  gemm(henc, jW1h, nullptr, penc, 2048, 512, 512, 512, 1024);
  gemm(hds, dPWh, dPb, hdec, 520, 512, 512, 512, 512);
  gemm(hdec, jW1h + 512, jb1, pdec, 520, 512, 512, 512, 1024);  // jb1 folded

  // 8) fused joint: z = tanh(penc+pdec) ; out = z @ jW2^T + jb2
  k_joint<<<dim3(1040), dim3(512), 133120, stream>>>(penc, pdec, jW2h, jb2, out);
}

// Round 3
// 2639.136 us; speedup vs baseline: 1.6666x; 1.0895x over previous
//
#include <hip/hip_runtime.h>

// ---------------------------------------------------------------------------
// Transducer forward (RNN-T). R2: all three LSTMs fused in ONE dispatch:
//   WGs  0-15 : encoder layer 0 (256 steps), publishes h0(t) per-step
//   WGs 16-31 : encoder layer 1 (256 steps), lag-1 pipeline; consumes h0(t),
//               computes h0(t)@Wih1^T + h1(t-1)@Whh1^T + b1 on the fly
//   WGs 32-47 : decoder (65 steps)
// Sync: RELAXED agent-scope atomics (LLC coherence point) + vmcnt drain via
// __syncthreads(); per-WG monotone flags. Weights live in VGPRs.
// ---------------------------------------------------------------------------

typedef _Float16 f16;
typedef _Float16 f16x8 __attribute__((ext_vector_type(8)));
typedef float f32x4 __attribute__((ext_vector_type(4)));
using u32 = unsigned int;

#define BB   8
#define TT   256
#define UU1  65      // U+1
#define HH   512
#define G4   2048    // 4*H
#define PP   512
#define JJ   512
#define VV   1024

#define LOADX(p)     __hip_atomic_load((p), __ATOMIC_RELAXED, __HIP_MEMORY_SCOPE_AGENT)
#define STOREX(p, v) __hip_atomic_store((p), (v), __ATOMIC_RELAXED, __HIP_MEMORY_SCOPE_AGENT)

static __device__ __forceinline__ u32 packf16(float a, float b) {
  f16 ha = (f16)a, hb = (f16)b;
  unsigned short ua = __builtin_bit_cast(unsigned short, ha);
  unsigned short ub = __builtin_bit_cast(unsigned short, hb);
  return (u32)ua | ((u32)ub << 16);
}
static __device__ __forceinline__ float sigm(float x) {
  x = fminf(30.f, fmaxf(-30.f, x));
  return __builtin_amdgcn_rcpf(1.f + __expf(-x));
}
static __device__ __forceinline__ float ftanh(float x) {
  x = fminf(15.f, fmaxf(-15.f, x));
  float t = __expf(2.f * x);
  return (t - 1.f) * __builtin_amdgcn_rcpf(t + 1.f);
}

// ---------------------------- utility kernels ------------------------------
__global__ void k_zero(u32* __restrict__ p, int n) {
  int i = blockIdx.x * 256 + threadIdx.x;
  if (i < n) p[i] = 0u;
}

__global__ void k_cast(const float* __restrict__ s, f16* __restrict__ d, int n4) {
  int i = blockIdx.x * 256 + threadIdx.x;
  if (i < n4) {
    const float4 v = *(const float4*)(s + (size_t)i * 4);
    u32 lo = packf16(v.x, v.y), hi = packf16(v.z, v.w);
    uint2 p; p.x = lo; p.y = hi;
    *(uint2*)(d + (size_t)i * 4) = p;
  }
}

// e[row][0:512] = embed[ys_p[row]] ; row = b*65+u ; ys_p[b][0]=BOS=0
__global__ void k_embed(const int* __restrict__ ys, const float* __restrict__ emb,
                        float* __restrict__ e) {
  int row = blockIdx.x;                 // 0..519
  int b = row / UU1, u = row % UU1;
  int idx = (u == 0) ? 0 : ys[b * (UU1 - 1) + (u - 1)];
  const float4* s = (const float4*)(emb + (size_t)idx * HH);
  float4* d = (float4*)(e + (size_t)row * HH);
  d[threadIdx.x] = s[threadIdx.x];      // 128 threads x 16B = 2KB
}

// ------------------------------ generic GEMM -------------------------------
// C[M,N] = A[M,lda](f32) * B[N,ldb](f16)^T (+ bias[n]); MFMA f16 16x16x32.
__global__ __launch_bounds__(256) void k_gemm(
    const float* __restrict__ A, const f16* __restrict__ B,
    const float* __restrict__ bias, float* __restrict__ C,
    int M, int N, int K, int lda, int ldb) {
  __shared__ f16 As[128][72];
  __shared__ f16 Bs[128][72];
  int tid = threadIdx.x;
  int mb = blockIdx.y * 128, nb = blockIdx.x * 128;
  int wave = tid >> 6, lane = tid & 63;
  int wm = wave >> 1, wn = wave & 1;
  int rowa = lane & 15, kg = lane >> 4;
  f32x4 acc[4][4] = {};
  for (int k0 = 0; k0 < K; k0 += 64) {
    for (int idx = tid; idx < 2048; idx += 256) {
      int r = idx >> 4, cq = idx & 15;
      int gm = mb + r, gk = k0 + cq * 4;
      float4 v = make_float4(0.f, 0.f, 0.f, 0.f);
      if (gm < M && gk + 3 < K) v = *(const float4*)(A + (size_t)gm * lda + gk);
      uint2 p; p.x = packf16(v.x, v.y); p.y = packf16(v.z, v.w);
      *(uint2*)&As[r][cq * 4] = p;
    }
    for (int idx = tid; idx < 1024; idx += 256) {
      int r = idx >> 3, c8 = idx & 7;
      int gn = nb + r, gk = k0 + c8 * 8;
      uint4 v = make_uint4(0u, 0u, 0u, 0u);
      if (gn < N && gk + 7 < K) v = *(const uint4*)(B + (size_t)gn * ldb + gk);
      *(uint4*)&Bs[r][c8 * 8] = v;
    }
    __syncthreads();
#pragma unroll
    for (int kf = 0; kf < 2; ++kf) {
      f16x8 af[4], bf[4];
#pragma unroll
      for (int mt = 0; mt < 4; ++mt)
        af[mt] = *(const f16x8*)&As[wm * 64 + mt * 16 + rowa][kf * 32 + kg * 8];
#pragma unroll
      for (int nt = 0; nt < 4; ++nt)
        bf[nt] = *(const f16x8*)&Bs[wn * 64 + nt * 16 + rowa][kf * 32 + kg * 8];
#pragma unroll
      for (int mt = 0; mt < 4; ++mt)
#pragma unroll
        for (int nt = 0; nt < 4; ++nt)
          acc[mt][nt] = __builtin_amdgcn_mfma_f32_16x16x32_f16(af[mt], bf[nt], acc[mt][nt], 0, 0, 0);
    }
    __syncthreads();
  }
#pragma unroll
  for (int nt = 0; nt < 4; ++nt) {
    int gn = nb + wn * 64 + nt * 16 + rowa;
    float bv = bias ? bias[gn] : 0.f;
#pragma unroll
    for (int mt = 0; mt < 4; ++mt)
#pragma unroll
      for (int r = 0; r < 4; ++r) {
        int gm = mb + wm * 64 + mt * 16 + kg * 4 + r;
        if (gm < M) C[(size_t)gm * N + gn] = acc[mt][nt][r] + bv;
      }
  }
}

// ------------------------------ persistent LSTM ----------------------------
// Unified per-layer body. WG wg owns hidden units [wg*32, wg*32+32).
//   xp    : [B*S][2048] precomputed input projection (incl. bias), or null
//   gb    : [2048] gate bias (used when xp==null), or null
//   Wih   : [2048][512] f16 input-to-hidden (used with hin), or null
//   Whh   : [2048][512] f16 hidden-to-hidden (always)
//   hin   : [S][2048] u32 per-step upstream h (f16 pairs), or null
//   inflg : upstream flags[16], or null
//   ring  : [2][2048] u32 self h ring (zero-init)
//   hstep : [S][2048] u32 per-step self h publish, or null
//   hs    : [B*S][512] f32 h output to HBM, or null
//   flags : self flags[16] (zero-init)
static __device__ __forceinline__ void lstm_core(
    int wg,
    const float* __restrict__ xp, const float* __restrict__ gb,
    const f16* __restrict__ Wih, const f16* __restrict__ Whh,
    const u32* __restrict__ hin, const int* __restrict__ inflg,
    u32* __restrict__ ring, u32* __restrict__ hstep,
    float* __restrict__ hs, int* __restrict__ flags, int S) {
  __shared__ f16 Hlds[16][520];
  __shared__ f16 Hlds2[16][520];
  __shared__ float gat[8][132];
  int tid = threadIdx.x;
  int u0 = wg * 32;
  int wave = tid >> 6, lane = tid & 63;
  int rowa = lane & 15, kg = lane >> 4;
  int b = tid >> 5, j = tid & 31;

  // Whh fragments -> registers (invariant over t).
  const f16* wbase = Whh + ((size_t)(wave * 512 + u0 + rowa)) * 512 + kg * 8;
  f16x8 wA0[16], wA1[16];
#pragma unroll
  for (int kf = 0; kf < 16; ++kf) {
    wA0[kf] = *(const f16x8*)(wbase + kf * 32);
    wA1[kf] = *(const f16x8*)(wbase + (size_t)16 * 512 + kf * 32);
  }
  f16x8 wB0[16], wB1[16];
  if (Wih) {
    const f16* wbase2 = Wih + ((size_t)(wave * 512 + u0 + rowa)) * 512 + kg * 8;
#pragma unroll
    for (int kf = 0; kf < 16; ++kf) {
      wB0[kf] = *(const f16x8*)(wbase2 + kf * 32);
      wB1[kf] = *(const f16x8*)(wbase2 + (size_t)16 * 512 + kf * 32);
    }
  }
  // gate bias (L1 path) hoisted
  float gbi = 0.f, gbf = 0.f, gbg = 0.f, gbo = 0.f;
  if (gb) {
    gbi = gb[u0 + j]; gbf = gb[512 + u0 + j];
    gbg = gb[1024 + u0 + j]; gbo = gb[1536 + u0 + j];
  }
  // zero LDS (rows 8..15 = M padding stay zero forever)
  for (int idx = tid; idx < 16 * 260; idx += 256) {
    ((u32*)Hlds)[idx] = 0u;
    ((u32*)Hlds2)[idx] = 0u;
  }

  float c = 0.f;
  for (int t = 0; t < S; ++t) {
    // wait: self h(t-1) ready (flags >= t) and upstream h(t) ready (inflg >= t+1)
    if (t > 0 && tid < 16) {
      int guard = 0;
      while (LOADX(flags + tid) < t && ++guard < (1 << 20)) { }
    }
    if (inflg && tid >= 16 && tid < 32) {
      int guard = 0;
      while (LOADX(inflg + (tid - 16)) < t + 1 && ++guard < (1 << 20)) { }
    }
    __syncthreads();  // B1

    // stage self h(t-1) from ring slot (t&1)
    {
      const u32* hb = ring + (size_t)(t & 1) * 2048;
      for (int k = 0; k < 8; ++k) {
        int idx = tid + k * 256;
        int r = idx >> 8, cu = idx & 255;
        ((u32*)Hlds)[r * 260 + cu] = LOADX(hb + r * 256 + cu);
      }
    }
    // stage upstream h(t)
    if (hin) {
      const u32* hb2 = hin + (size_t)t * 2048;
      for (int k = 0; k < 8; ++k) {
        int idx = tid + k * 256;
        int r = idx >> 8, cu = idx & 255;
        ((u32*)Hlds2)[r * 260 + cu] = LOADX(hb2 + r * 256 + cu);
      }
    }
    // xp gather issued here; consumed after B3 (hidden under staging+MFMA)
    float xi, xf, xg, xo;
    if (xp) {
      size_t xpo = ((size_t)b * S + t) * (size_t)G4 + u0 + j;
      xi = xp[xpo]; xf = xp[xpo + 512]; xg = xp[xpo + 1024]; xo = xp[xpo + 1536];
    } else {
      xi = gbi; xf = gbf; xg = gbg; xo = gbo;
    }
    __syncthreads();  // B2: LDS ready

    // gates = h(t-1) @ Whh_slice^T (+ h_in(t) @ Wih_slice^T)
    f32x4 acc0 = {0.f, 0.f, 0.f, 0.f}, acc1 = {0.f, 0.f, 0.f, 0.f};
#pragma unroll
    for (int kf = 0; kf < 16; ++kf) {
      f16x8 af = *(const f16x8*)&Hlds[rowa][kf * 32 + kg * 8];
      acc0 = __builtin_amdgcn_mfma_f32_16x16x32_f16(af, wA0[kf], acc0, 0, 0, 0);
      acc1 = __builtin_amdgcn_mfma_f32_16x16x32_f16(af, wA1[kf], acc1, 0, 0, 0);
    }
    if (Wih) {
#pragma unroll
      for (int kf = 0; kf < 16; ++kf) {
        f16x8 af = *(const f16x8*)&Hlds2[rowa][kf * 32 + kg * 8];
        acc0 = __builtin_amdgcn_mfma_f32_16x16x32_f16(af, wB0[kf], acc0, 0, 0, 0);
        acc1 = __builtin_amdgcn_mfma_f32_16x16x32_f16(af, wB1[kf], acc1, 0, 0, 0);
      }
    }
    if (kg < 2) {   // C rows 0..7 valid (batch), 8..15 are padding
#pragma unroll
      for (int r = 0; r < 4; ++r) {
        gat[kg * 4 + r][wave * 32 + rowa] = acc0[r];
        gat[kg * 4 + r][wave * 32 + 16 + rowa] = acc1[r];
      }
    }
    __syncthreads();  // B3: gat ready

    // scalar phase: thread -> (b, unit j)
    float gi = gat[b][j] + xi;
    float gf = gat[b][32 + j] + xf;
    float gg = gat[b][64 + j] + xg;
    float go = gat[b][96 + j] + xo;
    c = sigm(gf) * c + sigm(gi) * ftanh(gg);
    float h = sigm(go) * ftanh(c);

    float hn = __shfl_down(h, 1);
    if ((j & 1) == 0) {
      u32 pk = packf16(h, hn);
      int off = (b * 512 + u0 + j) >> 1;
      STOREX(ring + (size_t)((t + 1) & 1) * 2048 + off, pk);
      if (hstep) STOREX(hstep + (size_t)t * 2048 + off, pk);
    }
    __syncthreads();  // B4: drains vmcnt(0) -> h stores complete at LLC
    if (tid == 0) STOREX(&flags[wg], t + 1);
    if (hs) hs[((size_t)b * S + t) * HH + u0 + j] = h;  // overlaps next spin
  }
}

// all three LSTMs in one dispatch (48 WGs)
__global__ __launch_bounds__(256, 1) void k_lstm3(
    const float* xp0, const f16* Whh0, u32* ringA, u32* h0step, int* flA,
    const float* b1, const f16* Wih1, const f16* Whh1, u32* ringB,
    float* h1s, int* flB,
    const float* xpd, const f16* Whhd, u32* ringD, float* hds, int* flD) {
  int g = blockIdx.x;
  if (g < 16)
    lstm_core(g, xp0, nullptr, nullptr, Whh0, nullptr, nullptr,
              ringA, h0step, nullptr, flA, TT);
  else if (g < 32)
    lstm_core(g - 16, nullptr, b1, Wih1, Whh1, h0step, flA,
              ringB, nullptr, h1s, flB, TT);
  else
    lstm_core(g - 32, xpd, nullptr, nullptr, Whhd, nullptr, nullptr,
              ringD, nullptr, hds, flD, UU1);
}

// ------------------------------ fused joint --------------------------------
__global__ __launch_bounds__(512) void k_joint(
    const float* __restrict__ pre_enc,   // [B*T][512]   (no bias)
    const float* __restrict__ pre_dec,   // [B*65][512]  (jb1 folded in)
    const f16* __restrict__ jW2,         // [1024][512] f16
    const float* __restrict__ jb2,
    float* __restrict__ out) {
  extern __shared__ char smem[];
  f16 (*Z)[520] = (f16(*)[520])smem;     // 133,120 B
  int tid = threadIdx.x;
  int m0 = blockIdx.x * 128;
  {
    int r = tid >> 2, q = tid & 3;
    int m = m0 + r;
    int bb = m / (TT * UU1);
    int rem = m % (TT * UU1);
    int t = rem / UU1, u = rem % UU1;
    const float* pe = pre_enc + ((size_t)bb * TT + t) * JJ + q * 128;
    const float* pd = pre_dec + ((size_t)bb * UU1 + u) * JJ + q * 128;
    for (int i = 0; i < 128; i += 8) {
      float4 e0 = *(const float4*)(pe + i);
      float4 e1 = *(const float4*)(pe + i + 4);
      float4 d0 = *(const float4*)(pd + i);
      float4 d1 = *(const float4*)(pd + i + 4);
      float z0 = ftanh(e0.x + d0.x), z1 = ftanh(e0.y + d0.y);
      float z2 = ftanh(e0.z + d0.z), z3 = ftanh(e0.w + d0.w);
      float z4 = ftanh(e1.x + d1.x), z5 = ftanh(e1.y + d1.y);
      float z6 = ftanh(e1.z + d1.z), z7 = ftanh(e1.w + d1.w);
      uint4 p; p.x = packf16(z0, z1); p.y = packf16(z2, z3);
      p.z = packf16(z4, z5); p.w = packf16(z6, z7);
      *(uint4*)&Z[r][q * 128 + i] = p;
    }
  }
  __syncthreads();
  int wave = tid >> 6, lane = tid & 63;
  int wm = wave >> 2, wn = wave & 3;
  int rowa = lane & 15, kg = lane >> 4;
  for (int ch = 0; ch < 4; ++ch) {       // 4 N-chunks of 256
    f32x4 acc[4][4] = {};
    int nb = ch * 256 + wn * 64;
    for (int kf = 0; kf < 16; ++kf) {
      f16x8 af[4], bf[4];
#pragma unroll
      for (int mt = 0; mt < 4; ++mt)
        af[mt] = *(const f16x8*)&Z[wm * 64 + mt * 16 + rowa][kf * 32 + kg * 8];
#pragma unroll
      for (int nt = 0; nt < 4; ++nt)
        bf[nt] = *(const f16x8*)(jW2 + (size_t)(nb + nt * 16 + rowa) * JJ + kf * 32 + kg * 8);
#pragma unroll
      for (int mt = 0; mt < 4; ++mt)
#pragma unroll
        for (int nt = 0; nt < 4; ++nt)
          acc[mt][nt] = __builtin_amdgcn_mfma_f32_16x16x32_f16(af[mt], bf[nt], acc[mt][nt], 0, 0, 0);
    }
#pragma unroll
    for (int nt = 0; nt < 4; ++nt) {
      int v = nb + nt * 16 + rowa;
      float bv = jb2[v];
#pragma unroll
      for (int mt = 0; mt < 4; ++mt)
#pragma unroll
        for (int r = 0; r < 4; ++r) {
          int m = m0 + wm * 64 + mt * 16 + kg * 4 + r;
          out[(size_t)m * VV + v] = acc[mt][nt][r] + bv;
        }
    }
  }
}

// ------------------------------- host side ---------------------------------
extern "C" void kernel_launch(void* const* d_in, const int* in_sizes, int n_in,
                              void* d_out, int out_size, void* d_ws, size_t ws_size,
                              hipStream_t stream) {
  const float* xs    = (const float*)d_in[0];
  const int*   ys    = (const int*)d_in[1];
  const float* Wih0  = (const float*)d_in[2];
  const float* Whh0  = (const float*)d_in[3];
  const float* b0    = (const float*)d_in[4];
  const float* Wih1  = (const float*)d_in[5];
  const float* Whh1  = (const float*)d_in[6];
  const float* b1    = (const float*)d_in[7];
  const float* encPW = (const float*)d_in[8];
  const float* encPb = (const float*)d_in[9];
  const float* embed = (const float*)d_in[10];
  const float* dWih  = (const float*)d_in[11];
  const float* dWhh  = (const float*)d_in[12];
  const float* db    = (const float*)d_in[13];
  const float* dPW   = (const float*)d_in[14];
  const float* dPb   = (const float*)d_in[15];
  const float* jW1   = (const float*)d_in[16];
  const float* jb1   = (const float*)d_in[17];
  const float* jW2   = (const float*)d_in[18];
  const float* jb2   = (const float*)d_in[19];
  float* out = (float*)d_out;

  char* base = (char*)d_ws;
  size_t off = 0;
  auto alc = [&](size_t bytes) -> char* {
    char* p = base + off;
    off = (off + bytes + 255) & ~(size_t)255;
    return p;
  };
  f16* Wih0h = (f16*)alc((size_t)2048 * 80 * 2);
  f16* Whh0h = (f16*)alc((size_t)2048 * 512 * 2);
  f16* Wih1h = (f16*)alc((size_t)2048 * 512 * 2);
  f16* Whh1h = (f16*)alc((size_t)2048 * 512 * 2);
  f16* dWihh = (f16*)alc((size_t)2048 * 512 * 2);
  f16* dWhhh = (f16*)alc((size_t)2048 * 512 * 2);
  f16* ePWh  = (f16*)alc((size_t)512 * 512 * 2);
  f16* dPWh  = (f16*)alc((size_t)512 * 512 * 2);
  f16* jW1h  = (f16*)alc((size_t)512 * 1024 * 2);
  f16* jW2h  = (f16*)alc((size_t)1024 * 512 * 2);
  float* e    = (float*)alc((size_t)520 * 512 * 4);
  float* xp0  = (float*)alc((size_t)2048 * 2048 * 4);
  float* xpd  = (float*)alc((size_t)520 * 2048 * 4);
  float* h1s  = (float*)alc((size_t)2048 * 512 * 4);
  float* hds  = (float*)alc((size_t)520 * 512 * 4);
  float* henc = (float*)alc((size_t)2048 * 512 * 4);
  float* hdec = (float*)alc((size_t)520 * 512 * 4);
  float* penc = (float*)alc((size_t)2048 * 512 * 4);
  float* pdec = (float*)alc((size_t)520 * 512 * 4);
  u32* h0step = (u32*)alc((size_t)TT * 2048 * 4);      // per-step h0 publish
  char* sync_beg = alc(0);
  u32* ringA = (u32*)alc((size_t)2 * 2048 * 4);
  u32* ringB = (u32*)alc((size_t)2 * 2048 * 4);
  u32* ringD = (u32*)alc((size_t)2 * 2048 * 4);
  int* flA = (int*)alc(64);
  int* flB = (int*)alc(64);
  int* flD = (int*)alc(64);
  size_t zbytes = (size_t)((base + off) - sync_beg);
  if (off > ws_size) return;

  // 1) zero sync region (rings + flags) -- must precede the LSTM launch
  {
    int n = (int)(zbytes / 4);
    k_zero<<<dim3((n + 255) / 256), dim3(256), 0, stream>>>((u32*)sync_beg, n);
  }
  // 2) cast weights to f16
  auto cast = [&](const float* s, f16* d, size_t n) {
    int n4 = (int)(n / 4);
    k_cast<<<dim3((n4 + 255) / 256), dim3(256), 0, stream>>>(s, d, n4);
  };
  cast(Wih0, Wih0h, (size_t)2048 * 80);
  cast(Whh0, Whh0h, (size_t)2048 * 512);
  cast(Wih1, Wih1h, (size_t)2048 * 512);
  cast(Whh1, Whh1h, (size_t)2048 * 512);
  cast(dWih, dWihh, (size_t)2048 * 512);
  cast(dWhh, dWhhh, (size_t)2048 * 512);
  cast(encPW, ePWh, (size_t)512 * 512);
  cast(dPW, dPWh, (size_t)512 * 512);
  cast(jW1, jW1h, (size_t)512 * 1024);
  cast(jW2, jW2h, (size_t)1024 * 512);

  // 3) embedding (decoder input)
  k_embed<<<dim3(520), dim3(128), 0, stream>>>(ys, embed, e);

  auto gemm = [&](const float* A, const f16* B, const float* bias, float* C,
                  int M, int N, int K, int lda, int ldb) {
    k_gemm<<<dim3(N / 128, (M + 127) / 128), dim3(256), 0, stream>>>(
        A, B, bias, C, M, N, K, lda, ldb);
  };

  // 4) input projections for enc L0 and decoder
  gemm(xs, Wih0h, b0, xp0, 2048, 2048, 80, 80, 80);
  gemm(e, dWihh, db, xpd, 520, 2048, 512, 512, 512);

  // 5) all three LSTMs, pipelined, one dispatch (48 WGs)
  k_lstm3<<<dim3(48), dim3(256), 0, stream>>>(
      xp0, Whh0h, ringA, h0step, flA,
      b1, Wih1h, Whh1h, ringB, h1s, flB,
      xpd, dWhhh, ringD, hds, flD);

  // 6) projections / joint pre-activations
  gemm(h1s, ePWh, encPb, henc, 2048, 512, 512, 512, 512);
  gemm(henc, jW1h, nullptr, penc, 2048, 512, 512, 512, 1024);
  gemm(hds, dPWh, dPb, hdec, 520, 512, 512, 512, 512);
  gemm(hdec, jW1h + 512, jb1, pdec, 520, 512, 512, 512, 1024);  // jb1 folded

  // 7) fused joint: z = tanh(penc+pdec) ; out = z @ jW2^T + jb2
  k_joint<<<dim3(1040), dim3(512), 133120, stream>>>(penc, pdec, jW2h, jb2, out);
}

// Round 4
// 2359.372 us; speedup vs baseline: 1.8643x; 1.1186x over previous
//
#include <hip/hip_runtime.h>

// ---------------------------------------------------------------------------
// Transducer forward (RNN-T). R3: sentinel-synced persistent LSTMs.
//   WGs  0-15 : encoder L0 (256 steps), 32 units/WG, Whh0 in LDS
//   WGs 16-47 : encoder L1 (256 steps), 16 units/WG, [Whh1|Wih1] K=1024 in LDS
//   WGs 48-63 : decoder   (65 steps),  32 units/WG, dWhh in LDS
// h exchange: per-step write-once buffers hseq[t+1], pre-filled with sentinel
// 0xFFFFFFFF (f16 NaN pair; h in (-1,1) can never produce it). Consumers poll
// the data words directly -> one one-way LLC latency per step, no flags,
// no vmcnt-drain barrier. RELAXED agent-scope atomics throughout.
// ---------------------------------------------------------------------------

typedef _Float16 f16;
typedef _Float16 f16x8 __attribute__((ext_vector_type(8)));
typedef float f32x4 __attribute__((ext_vector_type(4)));
using u32 = unsigned int;

#define BB   8
#define TT   256
#define UU1  65      // U+1
#define HH   512
#define G4   2048    // 4*H
#define PP   512
#define JJ   512
#define VV   1024
#define SENT 0xFFFFFFFFu

#define LOADX(p)     __hip_atomic_load((p), __ATOMIC_RELAXED, __HIP_MEMORY_SCOPE_AGENT)
#define STOREX(p, v) __hip_atomic_store((p), (v), __ATOMIC_RELAXED, __HIP_MEMORY_SCOPE_AGENT)

static __device__ __forceinline__ u32 packf16(float a, float b) {
  f16 ha = (f16)a, hb = (f16)b;
  unsigned short ua = __builtin_bit_cast(unsigned short, ha);
  unsigned short ub = __builtin_bit_cast(unsigned short, hb);
  return (u32)ua | ((u32)ub << 16);
}
static __device__ __forceinline__ float sigm(float x) {
  x = fminf(30.f, fmaxf(-30.f, x));
  return __builtin_amdgcn_rcpf(1.f + __expf(-x));
}
static __device__ __forceinline__ float ftanh(float x) {
  x = fminf(15.f, fmaxf(-15.f, x));
  float t = __expf(2.f * x);
  return (t - 1.f) * __builtin_amdgcn_rcpf(t + 1.f);
}

// ---------------------------- utility kernels ------------------------------
__global__ void k_zero(u32* __restrict__ p, int n) {
  int i = blockIdx.x * 256 + threadIdx.x;
  if (i < n) p[i] = 0u;
}
__global__ void k_fill(u32* __restrict__ p, int n, u32 v) {
  int i = blockIdx.x * 256 + threadIdx.x;
  if (i < n) p[i] = v;
}

__global__ void k_cast(const float* __restrict__ s, f16* __restrict__ d, int n4) {
  int i = blockIdx.x * 256 + threadIdx.x;
  if (i < n4) {
    const float4 v = *(const float4*)(s + (size_t)i * 4);
    uint2 p; p.x = packf16(v.x, v.y); p.y = packf16(v.z, v.w);
    *(uint2*)(d + (size_t)i * 4) = p;
  }
}

// e[row][0:512] = embed[ys_p[row]] ; row = b*65+u ; ys_p[b][0]=BOS=0
__global__ void k_embed(const int* __restrict__ ys, const float* __restrict__ emb,
                        float* __restrict__ e) {
  int row = blockIdx.x;                 // 0..519
  int b = row / UU1, u = row % UU1;
  int idx = (u == 0) ? 0 : ys[b * (UU1 - 1) + (u - 1)];
  const float4* s = (const float4*)(emb + (size_t)idx * HH);
  float4* d = (float4*)(e + (size_t)row * HH);
  d[threadIdx.x] = s[threadIdx.x];      // 128 threads x 16B = 2KB
}

// ------------------------------ generic GEMM -------------------------------
// C[M,N] = A[M,lda](f32) * B[N,ldb](f16)^T (+ bias[n]); MFMA f16 16x16x32.
__global__ __launch_bounds__(256) void k_gemm(
    const float* __restrict__ A, const f16* __restrict__ B,
    const float* __restrict__ bias, float* __restrict__ C,
    int M, int N, int K, int lda, int ldb) {
  __shared__ f16 As[128][72];
  __shared__ f16 Bs[128][72];
  int tid = threadIdx.x;
  int mb = blockIdx.y * 128, nb = blockIdx.x * 128;
  int wave = tid >> 6, lane = tid & 63;
  int wm = wave >> 1, wn = wave & 1;
  int rowa = lane & 15, kg = lane >> 4;
  f32x4 acc[4][4] = {};
  for (int k0 = 0; k0 < K; k0 += 64) {
    for (int idx = tid; idx < 2048; idx += 256) {
      int r = idx >> 4, cq = idx & 15;
      int gm = mb + r, gk = k0 + cq * 4;
      float4 v = make_float4(0.f, 0.f, 0.f, 0.f);
      if (gm < M && gk + 3 < K) v = *(const float4*)(A + (size_t)gm * lda + gk);
      uint2 p; p.x = packf16(v.x, v.y); p.y = packf16(v.z, v.w);
      *(uint2*)&As[r][cq * 4] = p;
    }
    for (int idx = tid; idx < 1024; idx += 256) {
      int r = idx >> 3, c8 = idx & 7;
      int gn = nb + r, gk = k0 + c8 * 8;
      uint4 v = make_uint4(0u, 0u, 0u, 0u);
      if (gn < N && gk + 7 < K) v = *(const uint4*)(B + (size_t)gn * ldb + gk);
      *(uint4*)&Bs[r][c8 * 8] = v;
    }
    __syncthreads();
#pragma unroll
    for (int kf = 0; kf < 2; ++kf) {
      f16x8 af[4], bf[4];
#pragma unroll
      for (int mt = 0; mt < 4; ++mt)
        af[mt] = *(const f16x8*)&As[wm * 64 + mt * 16 + rowa][kf * 32 + kg * 8];
#pragma unroll
      for (int nt = 0; nt < 4; ++nt)
        bf[nt] = *(const f16x8*)&Bs[wn * 64 + nt * 16 + rowa][kf * 32 + kg * 8];
#pragma unroll
      for (int mt = 0; mt < 4; ++mt)
#pragma unroll
        for (int nt = 0; nt < 4; ++nt)
          acc[mt][nt] = __builtin_amdgcn_mfma_f32_16x16x32_f16(af[mt], bf[nt], acc[mt][nt], 0, 0, 0);
    }
    __syncthreads();
  }
#pragma unroll
  for (int nt = 0; nt < 4; ++nt) {
    int gn = nb + wn * 64 + nt * 16 + rowa;
    float bv = bias ? bias[gn] : 0.f;
#pragma unroll
    for (int mt = 0; mt < 4; ++mt)
#pragma unroll
      for (int r = 0; r < 4; ++r) {
        int gm = mb + wm * 64 + mt * 16 + kg * 4 + r;
        if (gm < M) C[(size_t)gm * N + gn] = acc[mt][nt][r] + bv;
      }
  }
}

// --------------------- persistent LSTM, sentinel-synced --------------------
// 32-unit WG (L0 / decoder): LDS W[128][520], H[8][520], gat[8][132].
static __device__ __forceinline__ void lstm_16(
    int wg, const float* __restrict__ xp, const f16* __restrict__ Whh,
    u32* __restrict__ hseq,   // [S+1][2048]; slot 0 zeroed, rest sentinel
    float* __restrict__ hs, int S) {
  extern __shared__ char smem[];
  f16 (*W)[520] = (f16(*)[520])smem;                       // 133,120 B
  f16 (*H)[520] = (f16(*)[520])(smem + 133120);            //   8,320 B
  float (*gat)[132] = (float(*)[132])(smem + 133120 + 8320);
  const int tid = threadIdx.x;
  const int u0 = wg * 32;
  const int wave = tid >> 6, lane = tid & 63;
  const int rowa = lane & 15, kg = lane >> 4;
  const int b = tid >> 5, j = tid & 31;

  // stage Whh slice: LDS row r = g*32+i <-> global row g*512 + u0 + i
  for (int idx = tid; idx < 128 * 64; idx += 256) {
    int r = idx >> 6, ck = idx & 63;
    int g = r >> 5, i = r & 31;
    uint4 v = *(const uint4*)(Whh + ((size_t)(g * 512 + u0 + i)) * 512 + ck * 8);
    *(uint4*)&W[r][ck * 8] = v;
  }
  __syncthreads();

  float c = 0.f;
  for (int t = 0; t < S; ++t) {
    // poll+stage h(t-1) = hseq[t]
    const u32* hb = hseq + (size_t)t * 2048;
#pragma unroll
    for (int k = 0; k < 8; ++k) {
      int idx = tid + k * 256;
      int r = idx >> 8, cu = idx & 255;
      u32 v; int gd = 0;
      do { v = LOADX(hb + r * 256 + cu); } while (v == SENT && ++gd < (1 << 22));
      ((u32*)H)[r * 260 + cu] = v;
    }
    size_t xpo = ((size_t)b * S + t) * (size_t)G4 + u0 + j;
    float xi = xp[xpo], xf = xp[xpo + 512], xg = xp[xpo + 1024], xo = xp[xpo + 1536];
    __syncthreads();  // B2: H ready

    f32x4 acc0 = {0.f, 0.f, 0.f, 0.f}, acc1 = {0.f, 0.f, 0.f, 0.f};
#pragma unroll
    for (int kf = 0; kf < 16; ++kf) {
      f16x8 af = {};
      if (rowa < 8) af = *(const f16x8*)&H[rowa][kf * 32 + kg * 8];
      f16x8 b0 = *(const f16x8*)&W[wave * 32 + rowa][kf * 32 + kg * 8];
      f16x8 b1 = *(const f16x8*)&W[wave * 32 + 16 + rowa][kf * 32 + kg * 8];
      acc0 = __builtin_amdgcn_mfma_f32_16x16x32_f16(af, b0, acc0, 0, 0, 0);
      acc1 = __builtin_amdgcn_mfma_f32_16x16x32_f16(af, b1, acc1, 0, 0, 0);
    }
    if (kg < 2) {   // C rows 0..7 valid (batch)
#pragma unroll
      for (int r = 0; r < 4; ++r) {
        gat[kg * 4 + r][wave * 32 + rowa] = acc0[r];
        gat[kg * 4 + r][wave * 32 + 16 + rowa] = acc1[r];
      }
    }
    __syncthreads();  // B3: gat ready

    float gi = gat[b][j] + xi;
    float gf = gat[b][32 + j] + xf;
    float gg = gat[b][64 + j] + xg;
    float go = gat[b][96 + j] + xo;
    c = sigm(gf) * c + sigm(gi) * ftanh(gg);
    float h = sigm(go) * ftanh(c);

    float hn = __shfl_down(h, 1);
    if ((j & 1) == 0)
      STOREX(hseq + (size_t)(t + 1) * 2048 + ((b * 512 + u0 + j) >> 1), packf16(h, hn));
    if (hs) hs[((size_t)b * S + t) * HH + u0 + j] = h;
  }
}

// 16-unit WG (encoder L1): K-concat [Whh1|Wih1].
// LDS W[64][1032], H[8][1032], gat[8][68]. 32 WGs.
static __device__ __forceinline__ void lstm_l1(
    int wg, const float* __restrict__ gb, const f16* __restrict__ Wih,
    const f16* __restrict__ Whh, const u32* __restrict__ hin,
    u32* __restrict__ hseq, float* __restrict__ hs, int S) {
  extern __shared__ char smem[];
  f16 (*W)[1032] = (f16(*)[1032])smem;                      // 132,096 B
  f16 (*H)[1032] = (f16(*)[1032])(smem + 132096);           //  16,512 B
  float (*gat)[68] = (float(*)[68])(smem + 132096 + 16512); //   2,176 B
  const int tid = threadIdx.x;
  const int u0 = wg * 16;
  const int wave = tid >> 6, lane = tid & 63;
  const int rowa = lane & 15, kg = lane >> 4;

  // stage weights: LDS row r = g*16+i <-> global row g*512 + u0 + i
  for (int idx = tid; idx < 64 * 64; idx += 256) {
    int r = idx >> 6, ck = idx & 63;
    int g = r >> 4, i = r & 15;
    size_t grow = (size_t)(g * 512 + u0 + i) * 512;
    *(uint4*)&W[r][ck * 8]       = *(const uint4*)(Whh + grow + ck * 8);
    *(uint4*)&W[r][512 + ck * 8] = *(const uint4*)(Wih + grow + ck * 8);
  }
  // bias (scalar-phase threads only)
  float gbi = 0.f, gbf = 0.f, gbg = 0.f, gbo = 0.f;
  if (tid < 128) {
    int jj = tid & 15;
    gbi = gb[u0 + jj]; gbf = gb[512 + u0 + jj];
    gbg = gb[1024 + u0 + jj]; gbo = gb[1536 + u0 + jj];
  }
  __syncthreads();

  float c = 0.f;
  for (int t = 0; t < S; ++t) {
    // poll+stage self h1(t-1) -> H[.., 0:512)
    {
      const u32* hb = hseq + (size_t)t * 2048;
#pragma unroll
      for (int k = 0; k < 8; ++k) {
        int idx = tid + k * 256;
        int r = idx >> 8, cu = idx & 255;
        u32 v; int gd = 0;
        do { v = LOADX(hb + r * 256 + cu); } while (v == SENT && ++gd < (1 << 22));
        ((u32*)H)[r * 516 + cu] = v;
      }
    }
    // poll+stage upstream h0(t) = hin[t+1] -> H[.., 512:1024)
    {
      const u32* hb = hin + (size_t)(t + 1) * 2048;
#pragma unroll
      for (int k = 0; k < 8; ++k) {
        int idx = tid + k * 256;
        int r = idx >> 8, cu = idx & 255;
        u32 v; int gd = 0;
        do { v = LOADX(hb + r * 256 + cu); } while (v == SENT && ++gd < (1 << 22));
        ((u32*)H)[r * 516 + 256 + cu] = v;
      }
    }
    __syncthreads();  // B2

    f32x4 acc = {0.f, 0.f, 0.f, 0.f};
#pragma unroll
    for (int kf = 0; kf < 32; ++kf) {
      f16x8 af = {};
      if (rowa < 8) af = *(const f16x8*)&H[rowa][kf * 32 + kg * 8];
      f16x8 bf = *(const f16x8*)&W[wave * 16 + rowa][kf * 32 + kg * 8];
      acc = __builtin_amdgcn_mfma_f32_16x16x32_f16(af, bf, acc, 0, 0, 0);
    }
    if (kg < 2) {   // wave w = gate w; col = unit offset rowa
#pragma unroll
      for (int r = 0; r < 4; ++r) gat[kg * 4 + r][wave * 16 + rowa] = acc[r];
    }
    __syncthreads();  // B3

    if (tid < 128) {
      int b = tid >> 4, j = tid & 15;
      float gi = gat[b][j]      + gbi;
      float gf = gat[b][16 + j] + gbf;
      float gg = gat[b][32 + j] + gbg;
      float go = gat[b][48 + j] + gbo;
      c = sigm(gf) * c + sigm(gi) * ftanh(gg);
      float h = sigm(go) * ftanh(c);
      float hn = __shfl_down(h, 1);
      if ((j & 1) == 0)
        STOREX(hseq + (size_t)(t + 1) * 2048 + (b * 256 + ((u0 + j) >> 1)), packf16(h, hn));
      hs[((size_t)b * S + t) * HH + u0 + j] = h;
    }
  }
}

// all three LSTMs in one dispatch (64 WGs)
__global__ __launch_bounds__(256, 1) void k_lstm3(
    const float* xp0, const f16* Whh0, u32* hseq0,
    const float* b1, const f16* Wih1, const f16* Whh1, u32* hseq1, float* h1s,
    const float* xpd, const f16* Whhd, u32* hseqD, float* hds) {
  int g = blockIdx.x;
  if (g < 16)      lstm_16(g, xp0, Whh0, hseq0, nullptr, TT);
  else if (g < 48) lstm_l1(g - 16, b1, Wih1, Whh1, hseq0, hseq1, h1s, TT);
  else             lstm_16(g - 48, xpd, Whhd, hseqD, hds, UU1);
}

// ------------------------------ fused joint --------------------------------
__global__ __launch_bounds__(512) void k_joint(
    const float* __restrict__ pre_enc,   // [B*T][512]   (no bias)
    const float* __restrict__ pre_dec,   // [B*65][512]  (jb1 folded in)
    const f16* __restrict__ jW2,         // [1024][512] f16
    const float* __restrict__ jb2,
    float* __restrict__ out) {
  extern __shared__ char smem[];
  f16 (*Z)[520] = (f16(*)[520])smem;     // 133,120 B
  int tid = threadIdx.x;
  int m0 = blockIdx.x * 128;
  {
    int r = tid >> 2, q = tid & 3;
    int m = m0 + r;
    int bb = m / (TT * UU1);
    int rem = m % (TT * UU1);
    int t = rem / UU1, u = rem % UU1;
    const float* pe = pre_enc + ((size_t)bb * TT + t) * JJ + q * 128;
    const float* pd = pre_dec + ((size_t)bb * UU1 + u) * JJ + q * 128;
    for (int i = 0; i < 128; i += 8) {
      float4 e0 = *(const float4*)(pe + i);
      float4 e1 = *(const float4*)(pe + i + 4);
      float4 d0 = *(const float4*)(pd + i);
      float4 d1 = *(const float4*)(pd + i + 4);
      float z0 = ftanh(e0.x + d0.x), z1 = ftanh(e0.y + d0.y);
      float z2 = ftanh(e0.z + d0.z), z3 = ftanh(e0.w + d0.w);
      float z4 = ftanh(e1.x + d1.x), z5 = ftanh(e1.y + d1.y);
      float z6 = ftanh(e1.z + d1.z), z7 = ftanh(e1.w + d1.w);
      uint4 p; p.x = packf16(z0, z1); p.y = packf16(z2, z3);
      p.z = packf16(z4, z5); p.w = packf16(z6, z7);
      *(uint4*)&Z[r][q * 128 + i] = p;
    }
  }
  __syncthreads();
  int wave = tid >> 6, lane = tid & 63;
  int wm = wave >> 2, wn = wave & 3;
  int rowa = lane & 15, kg = lane >> 4;
  for (int ch = 0; ch < 4; ++ch) {       // 4 N-chunks of 256
    f32x4 acc[4][4] = {};
    int nb = ch * 256 + wn * 64;
    for (int kf = 0; kf < 16; ++kf) {
      f16x8 af[4], bf[4];
#pragma unroll
      for (int mt = 0; mt < 4; ++mt)
        af[mt] = *(const f16x8*)&Z[wm * 64 + mt * 16 + rowa][kf * 32 + kg * 8];
#pragma unroll
      for (int nt = 0; nt < 4; ++nt)
        bf[nt] = *(const f16x8*)(jW2 + (size_t)(nb + nt * 16 + rowa) * JJ + kf * 32 + kg * 8);
#pragma unroll
      for (int mt = 0; mt < 4; ++mt)
#pragma unroll
        for (int nt = 0; nt < 4; ++nt)
          acc[mt][nt] = __builtin_amdgcn_mfma_f32_16x16x32_f16(af[mt], bf[nt], acc[mt][nt], 0, 0, 0);
    }
#pragma unroll
    for (int nt = 0; nt < 4; ++nt) {
      int v = nb + nt * 16 + rowa;
      float bv = jb2[v];
#pragma unroll
      for (int mt = 0; mt < 4; ++mt)
#pragma unroll
        for (int r = 0; r < 4; ++r) {
          int m = m0 + wm * 64 + mt * 16 + kg * 4 + r;
          out[(size_t)m * VV + v] = acc[mt][nt][r] + bv;
        }
    }
  }
}

// ------------------------------- host side ---------------------------------
extern "C" void kernel_launch(void* const* d_in, const int* in_sizes, int n_in,
                              void* d_out, int out_size, void* d_ws, size_t ws_size,
                              hipStream_t stream) {
  const float* xs    = (const float*)d_in[0];
  const int*   ys    = (const int*)d_in[1];
  const float* Wih0  = (const float*)d_in[2];
  const float* Whh0  = (const float*)d_in[3];
  const float* b0    = (const float*)d_in[4];
  const float* Wih1  = (const float*)d_in[5];
  const float* Whh1  = (const float*)d_in[6];
  const float* b1    = (const float*)d_in[7];
  const float* encPW = (const float*)d_in[8];
  const float* encPb = (const float*)d_in[9];
  const float* embed = (const float*)d_in[10];
  const float* dWih  = (const float*)d_in[11];
  const float* dWhh  = (const float*)d_in[12];
  const float* db    = (const float*)d_in[13];
  const float* dPW   = (const float*)d_in[14];
  const float* dPb   = (const float*)d_in[15];
  const float* jW1   = (const float*)d_in[16];
  const float* jb1   = (const float*)d_in[17];
  const float* jW2   = (const float*)d_in[18];
  const float* jb2   = (const float*)d_in[19];
  float* out = (float*)d_out;

  char* base = (char*)d_ws;
  size_t off = 0;
  auto alc = [&](size_t bytes) -> char* {
    char* p = base + off;
    off = (off + bytes + 255) & ~(size_t)255;
    return p;
  };
  f16* Wih0h = (f16*)alc((size_t)2048 * 80 * 2);
  f16* Whh0h = (f16*)alc((size_t)2048 * 512 * 2);
  f16* Wih1h = (f16*)alc((size_t)2048 * 512 * 2);
  f16* Whh1h = (f16*)alc((size_t)2048 * 512 * 2);
  f16* dWihh = (f16*)alc((size_t)2048 * 512 * 2);
  f16* dWhhh = (f16*)alc((size_t)2048 * 512 * 2);
  f16* ePWh  = (f16*)alc((size_t)512 * 512 * 2);
  f16* dPWh  = (f16*)alc((size_t)512 * 512 * 2);
  f16* jW1h  = (f16*)alc((size_t)512 * 1024 * 2);
  f16* jW2h  = (f16*)alc((size_t)1024 * 512 * 2);
  float* e    = (float*)alc((size_t)520 * 512 * 4);
  float* xp0  = (float*)alc((size_t)2048 * 2048 * 4);
  float* xpd  = (float*)alc((size_t)520 * 2048 * 4);
  float* h1s  = (float*)alc((size_t)2048 * 512 * 4);
  float* hds  = (float*)alc((size_t)520 * 512 * 4);
  float* henc = (float*)alc((size_t)2048 * 512 * 4);
  float* hdec = (float*)alc((size_t)520 * 512 * 4);
  float* penc = (float*)alc((size_t)2048 * 512 * 4);
  float* pdec = (float*)alc((size_t)520 * 512 * 4);
  // sentinel-synced h sequences (contiguous; sizes are 256-multiples)
  u32* hseq0 = (u32*)alc((size_t)(TT + 1) * 2048 * 4);   // [257][2048]
  u32* hseq1 = (u32*)alc((size_t)(TT + 1) * 2048 * 4);   // [257][2048]
  u32* hseqD = (u32*)alc((size_t)(UU1 + 1) * 2048 * 4);  // [66][2048]
  if (off > ws_size) return;

  // 1) sentinel-fill hseq region, then zero slot 0 of each (h(-1) = 0)
  {
    int n = (int)(((TT + 1) * 2 + (UU1 + 1)) * 2048);
    k_fill<<<dim3((n + 255) / 256), dim3(256), 0, stream>>>(hseq0, n, SENT);
    k_zero<<<dim3(8), dim3(256), 0, stream>>>(hseq0, 2048);
    k_zero<<<dim3(8), dim3(256), 0, stream>>>(hseq1, 2048);
    k_zero<<<dim3(8), dim3(256), 0, stream>>>(hseqD, 2048);
  }
  // 2) cast weights to f16
  auto cast = [&](const float* s, f16* d, size_t n) {
    int n4 = (int)(n / 4);
    k_cast<<<dim3((n4 + 255) / 256), dim3(256), 0, stream>>>(s, d, n4);
  };
  cast(Wih0, Wih0h, (size_t)2048 * 80);
  cast(Whh0, Whh0h, (size_t)2048 * 512);
  cast(Wih1, Wih1h, (size_t)2048 * 512);
  cast(Whh1, Whh1h, (size_t)2048 * 512);
  cast(dWih, dWihh, (size_t)2048 * 512);
  cast(dWhh, dWhhh, (size_t)2048 * 512);
  cast(encPW, ePWh, (size_t)512 * 512);
  cast(dPW, dPWh, (size_t)512 * 512);
  cast(jW1, jW1h, (size_t)512 * 1024);
  cast(jW2, jW2h, (size_t)1024 * 512);

  // 3) embedding (decoder input)
  k_embed<<<dim3(520), dim3(128), 0, stream>>>(ys, embed, e);

  auto gemm = [&](const float* A, const f16* B, const float* bias, float* C,
                  int M, int N, int K, int lda, int ldb) {
    k_gemm<<<dim3(N / 128, (M + 127) / 128), dim3(256), 0, stream>>>(
        A, B, bias, C, M, N, K, lda, ldb);
  };

  // 4) input projections for enc L0 and decoder
  gemm(xs, Wih0h, b0, xp0, 2048, 2048, 80, 80, 80);
  gemm(e, dWihh, db, xpd, 520, 2048, 512, 512, 512);

  // 5) all three LSTMs, sentinel-pipelined, one dispatch (64 WGs)
  k_lstm3<<<dim3(64), dim3(256), 150784, stream>>>(
      xp0, Whh0h, hseq0,
      b1, Wih1h, Whh1h, hseq1, h1s,
      xpd, dWhhh, hseqD, hds);

  // 6) projections / joint pre-activations
  gemm(h1s, ePWh, encPb, henc, 2048, 512, 512, 512, 512);
  gemm(henc, jW1h, nullptr, penc, 2048, 512, 512, 512, 1024);
  gemm(hds, dPWh, dPb, hdec, 520, 512, 512, 512, 512);
  gemm(hdec, jW1h + 512, jb1, pdec, 520, 512, 512, 512, 1024);  // jb1 folded

  // 7) fused joint: z = tanh(penc+pdec) ; out = z @ jW2^T + jb2
  k_joint<<<dim3(1040), dim3(512), 133120, stream>>>(penc, pdec, jW2h, jb2, out);
}